// Round 8
// baseline (404.045 us; speedup 1.0000x reference)
//
#include <hip/hip_runtime.h>

#define N_NODES 100000
constexpr int F     = 128;
constexpr int NB    = (N_NODES + 63) / 64;  // 1563 buckets of 64 dst-nodes
constexpr int BCAP  = 2560;                 // bucket capacity (mean 2048, +11 sigma)
constexpr int LCAP  = 80;                   // per-node LDS CSR cap (max in-deg ~65)
constexpr int CHUNK = 8192;                 // edges per partition block (391 blocks)
constexpr int PADN  = N_NODES;              // zero-row index for edge-list padding

typedef __attribute__((ext_vector_type(8))) short short8;   // 8 bf16 (4 VGPRs)
typedef __attribute__((ext_vector_type(4))) float f32x4;    // MFMA C/D
typedef __attribute__((ext_vector_type(4))) short short4v;
typedef __attribute__((ext_vector_type(4))) unsigned uint4v;

__device__ inline short f2bf(float v) {
    union { float f; unsigned u; } x; x.f = v;
    unsigned r = (x.u + 0x7fff + ((x.u >> 16) & 1)) >> 16;  // round-nearest-even
    return (short)r;
}
__device__ inline float lo_bf(unsigned v) {
    union { unsigned u; float f; } x; x.u = v << 16; return x.f;
}
__device__ inline float hi_bf(unsigned v) {
    union { unsigned u; float f; } x; x.u = v & 0xffff0000u; return x.f;
}

// ---------- weight prep (transpose->bf16) + bcr zeroing ----------
__global__ __launch_bounds__(256) void prep_kernel(const float* __restrict__ W_enc,
                                                   const float* __restrict__ W_gcn,
                                                   const float* __restrict__ W1,
                                                   const float* __restrict__ W2,
                                                   short* __restrict__ Wte,
                                                   short* __restrict__ Wtg,
                                                   short* __restrict__ Wt1,
                                                   short* __restrict__ W2t,
                                                   int* __restrict__ bcr) {
    int idx = blockIdx.x * 256 + threadIdx.x;
    if (idx < 16384) { int h = idx >> 7, k = idx & 127; Wte[idx] = f2bf(W_enc[k * 128 + h]); return; }
    idx -= 16384;
    if (idx < 16384) { int h = idx >> 7, k = idx & 127; Wtg[idx] = f2bf(W_gcn[k * 128 + h]); return; }
    idx -= 16384;
    if (idx < 32768) { int h = idx >> 7, k = idx & 127; Wt1[idx] = f2bf(W1[k * 256 + h]); return; }
    idx -= 32768;
    if (idx < 4096)  { int n = idx >> 8, k = idx & 255; W2t[idx] = (n < 10) ? f2bf(W2[k * 10 + n]) : (short)0; return; }
    idx -= 4096;
    if (idx < NB) bcr[idx] = 0;
}

// ---------- partition edges into 64-node dst-buckets (packed src | local_dst<<17) ----
__global__ __launch_bounds__(512) void part_kernel(const int* __restrict__ src,
                                                   const int* __restrict__ dst,
                                                   int* __restrict__ bcur,
                                                   int* __restrict__ part, int E) {
    __shared__ int cnt[NB];
    __shared__ int base[NB];
    for (int b = threadIdx.x; b < NB; b += 512) cnt[b] = 0;
    __syncthreads();
    const int e0 = blockIdx.x * CHUNK;
    const int e1 = min(e0 + CHUNK, E);
#pragma unroll 4
    for (int e = e0 + threadIdx.x; e < e1; e += 512)
        atomicAdd(&cnt[dst[e] >> 6], 1);
    __syncthreads();
    for (int b = threadIdx.x; b < NB; b += 512) {
        int c = cnt[b];
        base[b] = c ? atomicAdd(&bcur[b], c) : 0;
        cnt[b] = 0;  // reuse as local cursor
    }
    __syncthreads();
#pragma unroll 4
    for (int e = e0 + threadIdx.x; e < e1; e += 512) {
        int d = dst[e];
        int b = d >> 6;
        int idx = base[b] + atomicAdd(&cnt[b], 1);
        if (idx < BCAP) part[b * BCAP + idx] = src[e] | ((d & 63) << 17);
    }
}

// ---------- gemmA: degree scan + [relu(x@We+be)] -> LDS -> [(..@Wg)*dinv] -> xs ----
__global__ __launch_bounds__(256) void gemmA_kernel(const float* __restrict__ x,
                                                    const short* __restrict__ Wte,
                                                    const short* __restrict__ Wtg,
                                                    const float* __restrict__ b_enc,
                                                    const int* __restrict__ bcur,
                                                    const int* __restrict__ part,
                                                    short* __restrict__ xs) {
    __shared__ int deg_l[64];
    __shared__ short h_l[4][16][136];  // per-wave private 16x128 tiles (+pad)
    const int b = blockIdx.x;
    if (threadIdx.x < 64) deg_l[threadIdx.x] = 0;
    __syncthreads();
    const int cnt = min(bcur[b], BCAP);
    const int* p = part + (size_t)b * BCAP;
#pragma unroll 4
    for (int i = threadIdx.x; i < cnt; i += 256)
        atomicAdd(&deg_l[(p[i] >> 17) & 63], 1);

    const int wave = threadIdx.x >> 6;
    const int lane = threadIdx.x & 63;
    const int quad = lane >> 4;
    const int l16  = lane & 15;
    const int node0 = b * 64 + wave * 16;
    int nrow = node0 + l16;
    const bool valid = nrow < N_NODES;
    if (!valid) nrow = N_NODES - 1;

    // phase 1: h = relu(x @ W_enc + b_enc) -> LDS (bf16)
    f32x4 acc[8] = {};
#pragma unroll
    for (int kc = 0; kc < 4; ++kc) {
        const float* ap = x + (size_t)nrow * 128 + kc * 32 + quad * 8;
        float4 f0 = *reinterpret_cast<const float4*>(ap);
        float4 f1 = *reinterpret_cast<const float4*>(ap + 4);
        short8 xfrag;
        xfrag.s0 = f2bf(f0.x); xfrag.s1 = f2bf(f0.y); xfrag.s2 = f2bf(f0.z); xfrag.s3 = f2bf(f0.w);
        xfrag.s4 = f2bf(f1.x); xfrag.s5 = f2bf(f1.y); xfrag.s6 = f2bf(f1.z); xfrag.s7 = f2bf(f1.w);
#pragma unroll
        for (int t = 0; t < 8; ++t) {
            short8 wfrag = *reinterpret_cast<const short8*>(Wte + (size_t)(t * 16 + l16) * 128 + kc * 32 + quad * 8);
            acc[t] = __builtin_amdgcn_mfma_f32_16x16x32_bf16(wfrag, xfrag, acc[t], 0, 0, 0);
        }
    }
#pragma unroll
    for (int t = 0; t < 8; ++t) {
        short4v o;
#pragma unroll
        for (int r = 0; r < 4; ++r)
            ((short*)&o)[r] = f2bf(fmaxf(acc[t][r] + b_enc[t * 16 + quad * 4 + r], 0.f));
        *reinterpret_cast<short4v*>(&h_l[wave][l16][t * 16 + quad * 4]) = o;
    }
    __syncthreads();  // degree scan complete (h_l is wave-private)

    // phase 2: xs = (h @ W_gcn) * dinv[node]  (zero for pad rows)
    const float dvn = rsqrtf(1.f + (float)deg_l[wave * 16 + l16]);
    f32x4 acc2[8] = {};
#pragma unroll
    for (int kc = 0; kc < 4; ++kc) {
        short8 xfrag = *reinterpret_cast<const short8*>(&h_l[wave][l16][kc * 32 + quad * 8]);
#pragma unroll
        for (int t = 0; t < 8; ++t) {
            short8 wfrag = *reinterpret_cast<const short8*>(Wtg + (size_t)(t * 16 + l16) * 128 + kc * 32 + quad * 8);
            acc2[t] = __builtin_amdgcn_mfma_f32_16x16x32_bf16(wfrag, xfrag, acc2[t], 0, 0, 0);
        }
    }
    const int srow = node0 + l16;
#pragma unroll
    for (int t = 0; t < 8; ++t) {
        short4v o;
#pragma unroll
        for (int r = 0; r < 4; ++r)
            ((short*)&o)[r] = valid ? f2bf(acc2[t][r] * dvn) : (short)0;
        *reinterpret_cast<short4v*>(xs + (size_t)srow * 128 + t * 16 + quad * 4) = o;
    }
}

// ---------- fused agg + MLP with phased LDS arena (peak 38.1 KB -> 4 blocks/CU) ----
// gather phase: csr(20480)+cur(256)+h2_l(17408); MLP phase: hq_l(33792) overlays all.
__global__ __launch_bounds__(256, 4) void aggB_kernel(const short* __restrict__ xs,
                                                      const int* __restrict__ bcur,
                                                      const int* __restrict__ part,
                                                      const float* __restrict__ bg,
                                                      const short* __restrict__ Wt1,
                                                      const short* __restrict__ W2t,
                                                      const float* __restrict__ b1,
                                                      const float* __restrict__ b2,
                                                      float* __restrict__ q) {
    __shared__ char smem[38400];
    int*   csr_l = (int*)smem;                    // [0, 20480)
    int*   cur   = (int*)(smem + 20480);          // [20480, 20736)
    short* h2_l  = (short*)(smem + 20736);        // [20736, 38144)  [4][16][136]
    short* hq_l  = (short*)smem;                  // MLP phase: [0, 33792)  [4][16][264]

    const int b = blockIdx.x;
    const int tid = threadIdx.x;
    if (tid < 64) cur[tid] = 0;
    __syncthreads();
    const int cnt = min(bcur[b], BCAP);
    const int* p = part + (size_t)b * BCAP;
#pragma unroll 4
    for (int i = tid; i < cnt; i += 256) {
        int v = p[i];
        int ld = (v >> 17) & 63;
        int pos = atomicAdd(&cur[ld], 1);
        if (pos < LCAP) csr_l[ld * LCAP + pos] = v & 0x1FFFF;
    }
    __syncthreads();
    if (tid < 64) {  // pad each list to x8 with PADN (zero row)
        int d = min(cur[tid], LCAP);
        int dp = (d + 7) & ~7;
        for (int k = d; k < dp; ++k) csr_l[tid * LCAP + k] = PADN;
    }
    __syncthreads();

    const int wave = tid >> 6;
    const int lane = tid & 63;
    const int g    = lane >> 4;   // edge group
    const int l16  = lane & 15;   // 16 B feature slot
    const uint4v* xs4 = reinterpret_cast<const uint4v*>(xs);
    const float4 bgA = reinterpret_cast<const float4*>(bg)[l16 * 2];
    const float4 bgB = reinterpret_cast<const float4*>(bg)[l16 * 2 + 1];

    // ---- phase 1: gather -> h2 tile in LDS ----
    for (int t = 0; t < 16; ++t) {
        const int ld = wave * 16 + t;
        const int node = b * 64 + ld;
        if (node >= N_NODES) break;  // wave-uniform

        const int dtrue = cur[ld];
        const int dpad = (min(dtrue, LCAP) + 7) & ~7;
        const float dv = rsqrtf(1.f + (float)dtrue);
        const int* cl = csr_l + ld * LCAP;

        float a0 = 0.f, a1 = 0.f, a2 = 0.f, a3 = 0.f, a4 = 0.f, a5 = 0.f, a6 = 0.f, a7 = 0.f;
        for (int j = 0; j < dpad; j += 8) {
#pragma unroll
            for (int u = 0; u < 2; ++u) {
                int sj = cl[j + u * 4 + g];                    // 4-addr LDS broadcast
                uint4v v = xs4[((size_t)sj << 4) + l16];       // 16 B of the 256 B row
                a0 += lo_bf(v.x); a1 += hi_bf(v.x);
                a2 += lo_bf(v.y); a3 += hi_bf(v.y);
                a4 += lo_bf(v.z); a5 += hi_bf(v.z);
                a6 += lo_bf(v.w); a7 += hi_bf(v.w);
            }
        }
        // combine the 4 edge groups
        a0 += __shfl_xor(a0, 16, 64); a0 += __shfl_xor(a0, 32, 64);
        a1 += __shfl_xor(a1, 16, 64); a1 += __shfl_xor(a1, 32, 64);
        a2 += __shfl_xor(a2, 16, 64); a2 += __shfl_xor(a2, 32, 64);
        a3 += __shfl_xor(a3, 16, 64); a3 += __shfl_xor(a3, 32, 64);
        a4 += __shfl_xor(a4, 16, 64); a4 += __shfl_xor(a4, 32, 64);
        a5 += __shfl_xor(a5, 16, 64); a5 += __shfl_xor(a5, 32, 64);
        a6 += __shfl_xor(a6, 16, 64); a6 += __shfl_xor(a6, 32, 64);
        a7 += __shfl_xor(a7, 16, 64); a7 += __shfl_xor(a7, 32, 64);
        if (g == 0) {
            uint4v vs = xs4[((size_t)node << 4) + l16];  // self-loop
            a0 += lo_bf(vs.x); a1 += hi_bf(vs.x);
            a2 += lo_bf(vs.y); a3 += hi_bf(vs.y);
            a4 += lo_bf(vs.z); a5 += hi_bf(vs.z);
            a6 += lo_bf(vs.w); a7 += hi_bf(vs.w);
            short8 o;
            o.s0 = f2bf(fmaxf(fmaf(a0, dv, bgA.x), 0.f));
            o.s1 = f2bf(fmaxf(fmaf(a1, dv, bgA.y), 0.f));
            o.s2 = f2bf(fmaxf(fmaf(a2, dv, bgA.z), 0.f));
            o.s3 = f2bf(fmaxf(fmaf(a3, dv, bgA.w), 0.f));
            o.s4 = f2bf(fmaxf(fmaf(a4, dv, bgB.x), 0.f));
            o.s5 = f2bf(fmaxf(fmaf(a5, dv, bgB.y), 0.f));
            o.s6 = f2bf(fmaxf(fmaf(a6, dv, bgB.z), 0.f));
            o.s7 = f2bf(fmaxf(fmaf(a7, dv, bgB.w), 0.f));
            *reinterpret_cast<short8*>(h2_l + ((wave * 16 + t) * 136) + l16 * 8) = o;
        }
    }

    // ---- phase 2 preload: each wave pulls its 4 h2 A-frags into registers ----
    const int quad = lane >> 4;
    const int node0 = b * 64 + wave * 16;
    short8 h2frag[4];
#pragma unroll
    for (int kc = 0; kc < 4; ++kc)
        h2frag[kc] = *reinterpret_cast<const short8*>(h2_l + (wave * 16 + l16) * 136 + kc * 32 + quad * 8);
    __syncthreads();  // all csr/h2 reads done -> hq_l may overlay the whole arena

    // ---- phase 2: hq = relu(h2@W1+b1) -> LDS -> q = hq@W2 + b2 ----
    f32x4 acc[16] = {};
#pragma unroll
    for (int kc = 0; kc < 4; ++kc) {
#pragma unroll
        for (int t = 0; t < 16; ++t) {
            short8 wfrag = *reinterpret_cast<const short8*>(Wt1 + (size_t)(t * 16 + l16) * 128 + kc * 32 + quad * 8);
            acc[t] = __builtin_amdgcn_mfma_f32_16x16x32_bf16(wfrag, h2frag[kc], acc[t], 0, 0, 0);
        }
    }
#pragma unroll
    for (int t = 0; t < 16; ++t) {
        short4v o;
#pragma unroll
        for (int r = 0; r < 4; ++r)
            ((short*)&o)[r] = f2bf(fmaxf(acc[t][r] + b1[t * 16 + quad * 4 + r], 0.f));
        *reinterpret_cast<short4v*>(hq_l + (wave * 16 + l16) * 264 + t * 16 + quad * 4) = o;
    }
    // wave-private tile: ds_write -> ds_read ordered by lgkmcnt

    f32x4 a2 = {};
#pragma unroll
    for (int kc = 0; kc < 8; ++kc) {
        short8 afrag = *reinterpret_cast<const short8*>(hq_l + (wave * 16 + l16) * 264 + kc * 32 + quad * 8);
        short8 bfrag = *reinterpret_cast<const short8*>(W2t + (size_t)l16 * 256 + kc * 32 + quad * 8);
        a2 = __builtin_amdgcn_mfma_f32_16x16x32_bf16(afrag, bfrag, a2, 0, 0, 0);
    }
    if (l16 < 10) {
        float bv = b2[l16];
#pragma unroll
        for (int r = 0; r < 4; ++r) {
            int nd = node0 + quad * 4 + r;
            if (nd < N_NODES) q[(size_t)nd * 10 + l16] = a2[r] + bv;
        }
    }
}

extern "C" void kernel_launch(void* const* d_in, const int* in_sizes, int n_in,
                              void* d_out, int out_size, void* d_ws, size_t ws_size,
                              hipStream_t stream) {
    const float* x     = (const float*)d_in[0];
    const int*   ei    = (const int*)d_in[1];
    const float* W_enc = (const float*)d_in[2];
    const float* b_enc = (const float*)d_in[3];
    const float* W_gcn = (const float*)d_in[4];
    const float* b_gcn = (const float*)d_in[5];
    const float* W1    = (const float*)d_in[6];
    const float* b1    = (const float*)d_in[7];
    const float* W2    = (const float*)d_in[8];
    const float* b2    = (const float*)d_in[9];
    float* q = (float*)d_out;

    const int E = in_sizes[1] / 2;
    const int* srcv = ei;
    const int* dstv = ei + E;

    // workspace layout (bytes)
    char* ws = (char*)d_ws;
    const size_t XSB = (size_t)(NB * 64) * 128 * sizeof(short);  // 25,608,192 (incl. pad rows)
    short* xs  = (short*)(ws);
    int*   part= (int*)  (ws + XSB);                             // 16,005,120
    char*  tail = ws + XSB + (size_t)NB * BCAP * sizeof(int);
    int*   bcr = (int*)(tail);                                   // 8 KB slot
    short* Wte = (short*)(tail + 8192);
    short* Wtg = (short*)(tail + 8192 + 32768);
    short* Wt1 = (short*)(tail + 8192 + 65536);
    short* W2t = (short*)(tail + 8192 + 131072);
    // end ~= 42 MB

    prep_kernel<<<279, 256, 0, stream>>>(W_enc, W_gcn, W1, W2, Wte, Wtg, Wt1, W2t, bcr);
    part_kernel<<<(E + CHUNK - 1) / CHUNK, 512, 0, stream>>>(srcv, dstv, bcr, part, E);
    gemmA_kernel<<<NB, 256, 0, stream>>>(x, Wte, Wtg, b_enc, bcr, part, xs);
    aggB_kernel<<<NB, 256, 0, stream>>>(xs, bcr, part, b_gcn, Wt1, W2t, b1, b2, q);
}

// Round 9
// 397.936 us; speedup vs baseline: 1.0154x; 1.0154x over previous
//
#include <hip/hip_runtime.h>

#define N_NODES 100000
constexpr int F     = 128;
constexpr int NB    = (N_NODES + 63) / 64;  // 1563 buckets of 64 dst-nodes
constexpr int BCAP  = 2560;                 // bucket capacity (mean 2048, +11 sigma)
constexpr int LCAP  = 80;                   // per-node LDS CSR cap (max in-deg ~65)
constexpr int CHUNK = 8192;                 // edges per partition block (391 blocks)
constexpr int PADN  = N_NODES;              // zero-row index for edge-list padding

typedef __attribute__((ext_vector_type(8))) short short8;   // 8 bf16 (4 VGPRs)
typedef __attribute__((ext_vector_type(4))) float f32x4;    // MFMA C/D
typedef __attribute__((ext_vector_type(4))) short short4v;
typedef __attribute__((ext_vector_type(4))) unsigned uint4v;

__device__ inline short f2bf(float v) {
    union { float f; unsigned u; } x; x.f = v;
    unsigned r = (x.u + 0x7fff + ((x.u >> 16) & 1)) >> 16;  // round-nearest-even
    return (short)r;
}
__device__ inline float lo_bf(unsigned v) {
    union { unsigned u; float f; } x; x.u = v << 16; return x.f;
}
__device__ inline float hi_bf(unsigned v) {
    union { unsigned u; float f; } x; x.u = v & 0xffff0000u; return x.f;
}

// ---------- weight prep (transpose->bf16) + bcr zeroing ----------
__global__ __launch_bounds__(256) void prep_kernel(const float* __restrict__ W_enc,
                                                   const float* __restrict__ W_gcn,
                                                   const float* __restrict__ W1,
                                                   const float* __restrict__ W2,
                                                   short* __restrict__ Wte,
                                                   short* __restrict__ Wtg,
                                                   short* __restrict__ Wt1,
                                                   short* __restrict__ W2t,
                                                   int* __restrict__ bcr) {
    int idx = blockIdx.x * 256 + threadIdx.x;
    if (idx < 16384) { int h = idx >> 7, k = idx & 127; Wte[idx] = f2bf(W_enc[k * 128 + h]); return; }
    idx -= 16384;
    if (idx < 16384) { int h = idx >> 7, k = idx & 127; Wtg[idx] = f2bf(W_gcn[k * 128 + h]); return; }
    idx -= 16384;
    if (idx < 32768) { int h = idx >> 7, k = idx & 127; Wt1[idx] = f2bf(W1[k * 256 + h]); return; }
    idx -= 32768;
    if (idx < 4096)  { int n = idx >> 8, k = idx & 255; W2t[idx] = (n < 10) ? f2bf(W2[k * 10 + n]) : (short)0; return; }
    idx -= 4096;
    if (idx < NB) bcr[idx] = 0;
}

// ---------- partition edges into 64-node dst-buckets (packed src | local_dst<<17) ----
__global__ __launch_bounds__(512) void part_kernel(const int* __restrict__ src,
                                                   const int* __restrict__ dst,
                                                   int* __restrict__ bcur,
                                                   int* __restrict__ part, int E) {
    __shared__ int cnt[NB];
    __shared__ int base[NB];
    for (int b = threadIdx.x; b < NB; b += 512) cnt[b] = 0;
    __syncthreads();
    const int e0 = blockIdx.x * CHUNK;
    const int e1 = min(e0 + CHUNK, E);
#pragma unroll 4
    for (int e = e0 + threadIdx.x; e < e1; e += 512)
        atomicAdd(&cnt[dst[e] >> 6], 1);
    __syncthreads();
    for (int b = threadIdx.x; b < NB; b += 512) {
        int c = cnt[b];
        base[b] = c ? atomicAdd(&bcur[b], c) : 0;
        cnt[b] = 0;  // reuse as local cursor
    }
    __syncthreads();
#pragma unroll 4
    for (int e = e0 + threadIdx.x; e < e1; e += 512) {
        int d = dst[e];
        int b = d >> 6;
        int idx = base[b] + atomicAdd(&cnt[b], 1);
        if (idx < BCAP) part[b * BCAP + idx] = src[e] | ((d & 63) << 17);
    }
}

// ---------- gemmA: degree scan + [relu(x@We+be)] -> LDS -> [(..@Wg)*dinv] -> xs ----
__global__ __launch_bounds__(256) void gemmA_kernel(const float* __restrict__ x,
                                                    const short* __restrict__ Wte,
                                                    const short* __restrict__ Wtg,
                                                    const float* __restrict__ b_enc,
                                                    const int* __restrict__ bcur,
                                                    const int* __restrict__ part,
                                                    short* __restrict__ xs) {
    __shared__ int deg_l[64];
    __shared__ short h_l[4][16][136];  // per-wave private 16x128 tiles (+pad)
    const int b = blockIdx.x;
    if (threadIdx.x < 64) deg_l[threadIdx.x] = 0;
    __syncthreads();
    const int cnt = min(bcur[b], BCAP);
    const int* p = part + (size_t)b * BCAP;
#pragma unroll 4
    for (int i = threadIdx.x; i < cnt; i += 256)
        atomicAdd(&deg_l[(p[i] >> 17) & 63], 1);

    const int wave = threadIdx.x >> 6;
    const int lane = threadIdx.x & 63;
    const int quad = lane >> 4;
    const int l16  = lane & 15;
    const int node0 = b * 64 + wave * 16;
    int nrow = node0 + l16;
    const bool valid = nrow < N_NODES;
    if (!valid) nrow = N_NODES - 1;

    // phase 1: h = relu(x @ W_enc + b_enc) -> LDS (bf16)
    f32x4 acc[8] = {};
#pragma unroll
    for (int kc = 0; kc < 4; ++kc) {
        const float* ap = x + (size_t)nrow * 128 + kc * 32 + quad * 8;
        float4 f0 = *reinterpret_cast<const float4*>(ap);
        float4 f1 = *reinterpret_cast<const float4*>(ap + 4);
        short8 xfrag;
        xfrag.s0 = f2bf(f0.x); xfrag.s1 = f2bf(f0.y); xfrag.s2 = f2bf(f0.z); xfrag.s3 = f2bf(f0.w);
        xfrag.s4 = f2bf(f1.x); xfrag.s5 = f2bf(f1.y); xfrag.s6 = f2bf(f1.z); xfrag.s7 = f2bf(f1.w);
#pragma unroll
        for (int t = 0; t < 8; ++t) {
            short8 wfrag = *reinterpret_cast<const short8*>(Wte + (size_t)(t * 16 + l16) * 128 + kc * 32 + quad * 8);
            acc[t] = __builtin_amdgcn_mfma_f32_16x16x32_bf16(wfrag, xfrag, acc[t], 0, 0, 0);
        }
    }
#pragma unroll
    for (int t = 0; t < 8; ++t) {
        short4v o;
#pragma unroll
        for (int r = 0; r < 4; ++r)
            ((short*)&o)[r] = f2bf(fmaxf(acc[t][r] + b_enc[t * 16 + quad * 4 + r], 0.f));
        *reinterpret_cast<short4v*>(&h_l[wave][l16][t * 16 + quad * 4]) = o;
    }
    __syncthreads();  // degree scan complete (h_l is wave-private)

    // phase 2: xs = (h @ W_gcn) * dinv[node]  (zero for pad rows)
    const float dvn = rsqrtf(1.f + (float)deg_l[wave * 16 + l16]);
    f32x4 acc2[8] = {};
#pragma unroll
    for (int kc = 0; kc < 4; ++kc) {
        short8 xfrag = *reinterpret_cast<const short8*>(&h_l[wave][l16][kc * 32 + quad * 8]);
#pragma unroll
        for (int t = 0; t < 8; ++t) {
            short8 wfrag = *reinterpret_cast<const short8*>(Wtg + (size_t)(t * 16 + l16) * 128 + kc * 32 + quad * 8);
            acc2[t] = __builtin_amdgcn_mfma_f32_16x16x32_bf16(wfrag, xfrag, acc2[t], 0, 0, 0);
        }
    }
    const int srow = node0 + l16;
#pragma unroll
    for (int t = 0; t < 8; ++t) {
        short4v o;
#pragma unroll
        for (int r = 0; r < 4; ++r)
            ((short*)&o)[r] = valid ? f2bf(acc2[t][r] * dvn) : (short)0;
        *reinterpret_cast<short4v*>(xs + (size_t)srow * 128 + t * 16 + quad * 4) = o;
    }
}

// ---------- agg: h2 = relu(dv*(sum xs[src] + xs[node]) + b_gcn), 512-thread blocks ----
// 8 waves x 8 nodes; 4 lane-groups x 16 B; 16-edge unroll = 4 outstanding loads/lane.
__global__ __launch_bounds__(512, 8) void agg_kernel(const short* __restrict__ xs,
                                                     const int* __restrict__ bcur,
                                                     const int* __restrict__ part,
                                                     const float* __restrict__ bg,
                                                     short* __restrict__ h2) {
    __shared__ int csr_l[64 * LCAP];   // 20480 B
    __shared__ int cur[64];
    const int b = blockIdx.x;
    const int tid = threadIdx.x;
    if (tid < 64) cur[tid] = 0;
    __syncthreads();
    const int cnt = min(bcur[b], BCAP);
    const int* p = part + (size_t)b * BCAP;
#pragma unroll 4
    for (int i = tid; i < cnt; i += 512) {
        int v = p[i];
        int ld = (v >> 17) & 63;
        int pos = atomicAdd(&cur[ld], 1);
        if (pos < LCAP) csr_l[ld * LCAP + pos] = v & 0x1FFFF;
    }
    __syncthreads();
    if (tid < 64) {  // pad each list to x16 with PADN (zero row)
        int d = min(cur[tid], LCAP);
        int dp = (d + 15) & ~15;
        for (int k = d; k < dp; ++k) csr_l[tid * LCAP + k] = PADN;
    }
    __syncthreads();

    const int wave = tid >> 6;    // 0..7
    const int lane = tid & 63;
    const int g    = lane >> 4;   // edge group
    const int l16  = lane & 15;   // 16 B feature slot
    const uint4v* xs4 = reinterpret_cast<const uint4v*>(xs);
    const float4 bgA = reinterpret_cast<const float4*>(bg)[l16 * 2];
    const float4 bgB = reinterpret_cast<const float4*>(bg)[l16 * 2 + 1];

    for (int t = 0; t < 8; ++t) {
        const int ld = wave * 8 + t;
        const int node = b * 64 + ld;
        if (node >= N_NODES) break;  // wave-uniform

        const int dtrue = cur[ld];
        const int dpad = (min(dtrue, LCAP) + 15) & ~15;
        const float dv = rsqrtf(1.f + (float)dtrue);
        const int* cl = csr_l + ld * LCAP;

        float a0 = 0.f, a1 = 0.f, a2 = 0.f, a3 = 0.f, a4 = 0.f, a5 = 0.f, a6 = 0.f, a7 = 0.f;
        for (int j = 0; j < dpad; j += 16) {
            int s[4];
            uint4v v[4];
#pragma unroll
            for (int u = 0; u < 4; ++u) s[u] = cl[j + u * 4 + g];   // 4-addr LDS broadcast
#pragma unroll
            for (int u = 0; u < 4; ++u) v[u] = xs4[((size_t)s[u] << 4) + l16];  // 4 in flight
#pragma unroll
            for (int u = 0; u < 4; ++u) {
                a0 += lo_bf(v[u].x); a1 += hi_bf(v[u].x);
                a2 += lo_bf(v[u].y); a3 += hi_bf(v[u].y);
                a4 += lo_bf(v[u].z); a5 += hi_bf(v[u].z);
                a6 += lo_bf(v[u].w); a7 += hi_bf(v[u].w);
            }
        }
        // combine the 4 edge groups
        a0 += __shfl_xor(a0, 16, 64); a0 += __shfl_xor(a0, 32, 64);
        a1 += __shfl_xor(a1, 16, 64); a1 += __shfl_xor(a1, 32, 64);
        a2 += __shfl_xor(a2, 16, 64); a2 += __shfl_xor(a2, 32, 64);
        a3 += __shfl_xor(a3, 16, 64); a3 += __shfl_xor(a3, 32, 64);
        a4 += __shfl_xor(a4, 16, 64); a4 += __shfl_xor(a4, 32, 64);
        a5 += __shfl_xor(a5, 16, 64); a5 += __shfl_xor(a5, 32, 64);
        a6 += __shfl_xor(a6, 16, 64); a6 += __shfl_xor(a6, 32, 64);
        a7 += __shfl_xor(a7, 16, 64); a7 += __shfl_xor(a7, 32, 64);
        if (g == 0) {
            uint4v vs = xs4[((size_t)node << 4) + l16];  // self-loop
            a0 += lo_bf(vs.x); a1 += hi_bf(vs.x);
            a2 += lo_bf(vs.y); a3 += hi_bf(vs.y);
            a4 += lo_bf(vs.z); a5 += hi_bf(vs.z);
            a6 += lo_bf(vs.w); a7 += hi_bf(vs.w);
            short8 o;
            o.s0 = f2bf(fmaxf(fmaf(a0, dv, bgA.x), 0.f));
            o.s1 = f2bf(fmaxf(fmaf(a1, dv, bgA.y), 0.f));
            o.s2 = f2bf(fmaxf(fmaf(a2, dv, bgA.z), 0.f));
            o.s3 = f2bf(fmaxf(fmaf(a3, dv, bgA.w), 0.f));
            o.s4 = f2bf(fmaxf(fmaf(a4, dv, bgB.x), 0.f));
            o.s5 = f2bf(fmaxf(fmaf(a5, dv, bgB.y), 0.f));
            o.s6 = f2bf(fmaxf(fmaf(a6, dv, bgB.z), 0.f));
            o.s7 = f2bf(fmaxf(fmaf(a7, dv, bgB.w), 0.f));
            *reinterpret_cast<short8*>(h2 + ((size_t)node << 7) + l16 * 8) = o;
        }
    }
}

// ---------- gemmB: hq = relu(h2@W1+b1) -> LDS -> q = hq@W2 + b2 ----------
__global__ __launch_bounds__(256) void gemmB_kernel(const short* __restrict__ h2,
                                                    const short* __restrict__ Wt1,
                                                    const short* __restrict__ W2t,
                                                    const float* __restrict__ b1,
                                                    const float* __restrict__ b2,
                                                    float* __restrict__ q) {
    __shared__ short hq_l[4][16][264];  // per-wave private 16x256 tiles (+pad)
    const int wave = threadIdx.x >> 6;
    const int lane = threadIdx.x & 63;
    const int quad = lane >> 4;
    const int l16  = lane & 15;
    const int node0 = blockIdx.x * 64 + wave * 16;
    int nrow = node0 + l16;
    if (nrow >= N_NODES) nrow = N_NODES - 1;

    f32x4 acc[16] = {};
#pragma unroll
    for (int kc = 0; kc < 4; ++kc) {
        short8 xfrag = *reinterpret_cast<const short8*>(h2 + (size_t)nrow * 128 + kc * 32 + quad * 8);
#pragma unroll
        for (int t = 0; t < 16; ++t) {
            short8 wfrag = *reinterpret_cast<const short8*>(Wt1 + (size_t)(t * 16 + l16) * 128 + kc * 32 + quad * 8);
            acc[t] = __builtin_amdgcn_mfma_f32_16x16x32_bf16(wfrag, xfrag, acc[t], 0, 0, 0);
        }
    }
#pragma unroll
    for (int t = 0; t < 16; ++t) {
        short4v o;
#pragma unroll
        for (int r = 0; r < 4; ++r)
            ((short*)&o)[r] = f2bf(fmaxf(acc[t][r] + b1[t * 16 + quad * 4 + r], 0.f));
        *reinterpret_cast<short4v*>(&hq_l[wave][l16][t * 16 + quad * 4]) = o;
    }
    // wave-private tile: ds_write -> ds_read ordered by lgkmcnt

    f32x4 a2 = {};
#pragma unroll
    for (int kc = 0; kc < 8; ++kc) {
        short8 afrag = *reinterpret_cast<const short8*>(&hq_l[wave][l16][kc * 32 + quad * 8]);
        short8 bfrag = *reinterpret_cast<const short8*>(W2t + (size_t)l16 * 256 + kc * 32 + quad * 8);
        a2 = __builtin_amdgcn_mfma_f32_16x16x32_bf16(afrag, bfrag, a2, 0, 0, 0);
    }
    if (l16 < 10) {
        float bv = b2[l16];
#pragma unroll
        for (int r = 0; r < 4; ++r) {
            int nd = node0 + quad * 4 + r;
            if (nd < N_NODES) q[(size_t)nd * 10 + l16] = a2[r] + bv;
        }
    }
}

extern "C" void kernel_launch(void* const* d_in, const int* in_sizes, int n_in,
                              void* d_out, int out_size, void* d_ws, size_t ws_size,
                              hipStream_t stream) {
    const float* x     = (const float*)d_in[0];
    const int*   ei    = (const int*)d_in[1];
    const float* W_enc = (const float*)d_in[2];
    const float* b_enc = (const float*)d_in[3];
    const float* W_gcn = (const float*)d_in[4];
    const float* b_gcn = (const float*)d_in[5];
    const float* W1    = (const float*)d_in[6];
    const float* b1    = (const float*)d_in[7];
    const float* W2    = (const float*)d_in[8];
    const float* b2    = (const float*)d_in[9];
    float* q = (float*)d_out;

    const int E = in_sizes[1] / 2;
    const int* srcv = ei;
    const int* dstv = ei + E;

    // workspace layout (bytes)
    char* ws = (char*)d_ws;
    const size_t XSB = (size_t)(NB * 64) * 128 * sizeof(short);  // 25,608,192 (incl. pad rows)
    short* xs  = (short*)(ws);
    short* h2  = (short*)(ws + XSB);
    int*   part= (int*)  (ws + 2 * XSB);                         // 16,005,120
    char*  tail = ws + 2 * XSB + (size_t)NB * BCAP * sizeof(int);
    int*   bcr = (int*)(tail);                                   // 8 KB slot
    short* Wte = (short*)(tail + 8192);
    short* Wtg = (short*)(tail + 8192 + 32768);
    short* Wt1 = (short*)(tail + 8192 + 65536);
    short* W2t = (short*)(tail + 8192 + 131072);
    // end ~= 67.7 MB

    prep_kernel<<<279, 256, 0, stream>>>(W_enc, W_gcn, W1, W2, Wte, Wtg, Wt1, W2t, bcr);
    part_kernel<<<(E + CHUNK - 1) / CHUNK, 512, 0, stream>>>(srcv, dstv, bcr, part, E);
    gemmA_kernel<<<NB, 256, 0, stream>>>(x, Wte, Wtg, b_enc, bcr, part, xs);
    agg_kernel<<<NB, 512, 0, stream>>>(xs, bcr, part, b_gcn, h2);
    gemmB_kernel<<<NB, 256, 0, stream>>>(h2, Wt1, W2t, b1, b2, q);
}

// Round 10
// 388.022 us; speedup vs baseline: 1.0413x; 1.0255x over previous
//
#include <hip/hip_runtime.h>

#define N_NODES 100000
constexpr int F     = 128;
constexpr int NB    = (N_NODES + 63) / 64;  // 1563 buckets of 64 dst-nodes
constexpr int BCAP  = 2560;                 // bucket capacity (mean 2048, +11 sigma)
constexpr int LCAP  = 80;                   // per-node LDS CSR cap (max in-deg ~65)
constexpr int CHUNK = 8192;                 // edges per partition block (391 blocks)
constexpr int EPT   = CHUNK / 512;          // 16 edges per thread (registers)
constexpr int PADN  = N_NODES;              // zero-row index for edge-list padding

typedef __attribute__((ext_vector_type(8))) short short8;   // 8 bf16 (4 VGPRs)
typedef __attribute__((ext_vector_type(4))) float f32x4;    // MFMA C/D
typedef __attribute__((ext_vector_type(4))) short short4v;
typedef __attribute__((ext_vector_type(4))) unsigned uint4v;

__device__ inline short f2bf(float v) {
    union { float f; unsigned u; } x; x.f = v;
    unsigned r = (x.u + 0x7fff + ((x.u >> 16) & 1)) >> 16;  // round-nearest-even
    return (short)r;
}
__device__ inline float lo_bf(unsigned v) {
    union { unsigned u; float f; } x; x.u = v << 16; return x.f;
}
__device__ inline float hi_bf(unsigned v) {
    union { unsigned u; float f; } x; x.u = v & 0xffff0000u; return x.f;
}

// ---------- weight prep (transpose->bf16) + bcr zeroing ----------
__global__ __launch_bounds__(256) void prep_kernel(const float* __restrict__ W_enc,
                                                   const float* __restrict__ W_gcn,
                                                   const float* __restrict__ W1,
                                                   const float* __restrict__ W2,
                                                   short* __restrict__ Wte,
                                                   short* __restrict__ Wtg,
                                                   short* __restrict__ Wt1,
                                                   short* __restrict__ W2t,
                                                   int* __restrict__ bcr) {
    int idx = blockIdx.x * 256 + threadIdx.x;
    if (idx < 16384) { int h = idx >> 7, k = idx & 127; Wte[idx] = f2bf(W_enc[k * 128 + h]); return; }
    idx -= 16384;
    if (idx < 16384) { int h = idx >> 7, k = idx & 127; Wtg[idx] = f2bf(W_gcn[k * 128 + h]); return; }
    idx -= 16384;
    if (idx < 32768) { int h = idx >> 7, k = idx & 127; Wt1[idx] = f2bf(W1[k * 256 + h]); return; }
    idx -= 32768;
    if (idx < 4096)  { int n = idx >> 8, k = idx & 255; W2t[idx] = (n < 10) ? f2bf(W2[k * 10 + n]) : (short)0; return; }
    idx -= 4096;
    if (idx < NB) bcr[idx] = 0;
}

// ---------- single-pass partition: edges read once, pos from the count atomic ----
__global__ __launch_bounds__(512, 4) void part_kernel(const int* __restrict__ src,
                                                      const int* __restrict__ dst,
                                                      int* __restrict__ bcur,
                                                      int* __restrict__ part, int E) {
    __shared__ int cnt[NB];
    __shared__ int base[NB];
    for (int b = threadIdx.x; b < NB; b += 512) cnt[b] = 0;
    __syncthreads();
    const int e0 = blockIdx.x * CHUNK;
    const int e1 = min(e0 + CHUNK, E);

    int pk[EPT];    // src | local_dst<<17
    int meta[EPT];  // bucket | pos<<11  (or -1 invalid)
#pragma unroll
    for (int i = 0; i < EPT; ++i) {
        int e = e0 + i * 512 + (int)threadIdx.x;
        meta[i] = -1;
        if (e < e1) {
            int d = dst[e];
            int b = d >> 6;
            pk[i] = src[e] | ((d & 63) << 17);
            int pos = atomicAdd(&cnt[b], 1);
            meta[i] = b | (pos << 11);
        }
    }
    __syncthreads();
    for (int b = threadIdx.x; b < NB; b += 512) {
        int c = cnt[b];
        base[b] = c ? atomicAdd(&bcur[b], c) : 0;
    }
    __syncthreads();
#pragma unroll
    for (int i = 0; i < EPT; ++i) {
        if (meta[i] >= 0) {
            int b = meta[i] & 0x7FF;
            int idx = base[b] + (meta[i] >> 11);
            if (idx < BCAP) part[b * BCAP + idx] = pk[i];
        }
    }
}

// ---------- gemmA: degree scan + [relu(x@We+be)] -> LDS -> [(..@Wg)*dinv] -> xs ----
__global__ __launch_bounds__(256) void gemmA_kernel(const float* __restrict__ x,
                                                    const short* __restrict__ Wte,
                                                    const short* __restrict__ Wtg,
                                                    const float* __restrict__ b_enc,
                                                    const int* __restrict__ bcur,
                                                    const int* __restrict__ part,
                                                    short* __restrict__ xs) {
    __shared__ int deg_l[64];
    __shared__ short h_l[4][16][136];  // per-wave private 16x128 tiles (+pad)
    const int b = blockIdx.x;
    if (threadIdx.x < 64) deg_l[threadIdx.x] = 0;
    __syncthreads();
    const int cnt = min(bcur[b], BCAP);
    const int* p = part + (size_t)b * BCAP;
#pragma unroll 4
    for (int i = threadIdx.x; i < cnt; i += 256)
        atomicAdd(&deg_l[(p[i] >> 17) & 63], 1);

    const int wave = threadIdx.x >> 6;
    const int lane = threadIdx.x & 63;
    const int quad = lane >> 4;
    const int l16  = lane & 15;
    const int node0 = b * 64 + wave * 16;
    int nrow = node0 + l16;
    const bool valid = nrow < N_NODES;
    if (!valid) nrow = N_NODES - 1;

    // phase 1: h = relu(x @ W_enc + b_enc) -> LDS (bf16)
    f32x4 acc[8] = {};
#pragma unroll
    for (int kc = 0; kc < 4; ++kc) {
        const float* ap = x + (size_t)nrow * 128 + kc * 32 + quad * 8;
        float4 f0 = *reinterpret_cast<const float4*>(ap);
        float4 f1 = *reinterpret_cast<const float4*>(ap + 4);
        short8 xfrag;
        xfrag.s0 = f2bf(f0.x); xfrag.s1 = f2bf(f0.y); xfrag.s2 = f2bf(f0.z); xfrag.s3 = f2bf(f0.w);
        xfrag.s4 = f2bf(f1.x); xfrag.s5 = f2bf(f1.y); xfrag.s6 = f2bf(f1.z); xfrag.s7 = f2bf(f1.w);
#pragma unroll
        for (int t = 0; t < 8; ++t) {
            short8 wfrag = *reinterpret_cast<const short8*>(Wte + (size_t)(t * 16 + l16) * 128 + kc * 32 + quad * 8);
            acc[t] = __builtin_amdgcn_mfma_f32_16x16x32_bf16(wfrag, xfrag, acc[t], 0, 0, 0);
        }
    }
#pragma unroll
    for (int t = 0; t < 8; ++t) {
        short4v o;
#pragma unroll
        for (int r = 0; r < 4; ++r)
            ((short*)&o)[r] = f2bf(fmaxf(acc[t][r] + b_enc[t * 16 + quad * 4 + r], 0.f));
        *reinterpret_cast<short4v*>(&h_l[wave][l16][t * 16 + quad * 4]) = o;
    }
    __syncthreads();  // degree scan complete (h_l is wave-private)

    // phase 2: xs = (h @ W_gcn) * dinv[node]  (zero for pad rows)
    const float dvn = rsqrtf(1.f + (float)deg_l[wave * 16 + l16]);
    f32x4 acc2[8] = {};
#pragma unroll
    for (int kc = 0; kc < 4; ++kc) {
        short8 xfrag = *reinterpret_cast<const short8*>(&h_l[wave][l16][kc * 32 + quad * 8]);
#pragma unroll
        for (int t = 0; t < 8; ++t) {
            short8 wfrag = *reinterpret_cast<const short8*>(Wtg + (size_t)(t * 16 + l16) * 128 + kc * 32 + quad * 8);
            acc2[t] = __builtin_amdgcn_mfma_f32_16x16x32_bf16(wfrag, xfrag, acc2[t], 0, 0, 0);
        }
    }
    const int srow = node0 + l16;
#pragma unroll
    for (int t = 0; t < 8; ++t) {
        short4v o;
#pragma unroll
        for (int r = 0; r < 4; ++r)
            ((short*)&o)[r] = valid ? f2bf(acc2[t][r] * dvn) : (short)0;
        *reinterpret_cast<short4v*>(xs + (size_t)srow * 128 + t * 16 + quad * 4) = o;
    }
}

// ---------- agg: h2 = relu(dv*(sum xs[src] + xs[node]) + b_gcn), 512-thread blocks ----
__global__ __launch_bounds__(512, 8) void agg_kernel(const short* __restrict__ xs,
                                                     const int* __restrict__ bcur,
                                                     const int* __restrict__ part,
                                                     const float* __restrict__ bg,
                                                     short* __restrict__ h2) {
    __shared__ int csr_l[64 * LCAP];   // 20480 B
    __shared__ int cur[64];
    const int b = blockIdx.x;
    const int tid = threadIdx.x;
    if (tid < 64) cur[tid] = 0;
    __syncthreads();
    const int cnt = min(bcur[b], BCAP);
    const int* p = part + (size_t)b * BCAP;
#pragma unroll 4
    for (int i = tid; i < cnt; i += 512) {
        int v = p[i];
        int ld = (v >> 17) & 63;
        int pos = atomicAdd(&cur[ld], 1);
        if (pos < LCAP) csr_l[ld * LCAP + pos] = v & 0x1FFFF;
    }
    __syncthreads();
    if (tid < 64) {  // pad each list to x16 with PADN (zero row)
        int d = min(cur[tid], LCAP);
        int dp = (d + 15) & ~15;
        for (int k = d; k < dp; ++k) csr_l[tid * LCAP + k] = PADN;
    }
    __syncthreads();

    const int wave = tid >> 6;    // 0..7
    const int lane = tid & 63;
    const int g    = lane >> 4;   // edge group
    const int l16  = lane & 15;   // 16 B feature slot
    const uint4v* xs4 = reinterpret_cast<const uint4v*>(xs);
    const float4 bgA = reinterpret_cast<const float4*>(bg)[l16 * 2];
    const float4 bgB = reinterpret_cast<const float4*>(bg)[l16 * 2 + 1];

    for (int t = 0; t < 8; ++t) {
        const int ld = wave * 8 + t;
        const int node = b * 64 + ld;
        if (node >= N_NODES) break;  // wave-uniform

        const int dtrue = cur[ld];
        const int dpad = (min(dtrue, LCAP) + 15) & ~15;
        const float dv = rsqrtf(1.f + (float)dtrue);
        const int* cl = csr_l + ld * LCAP;

        float a0 = 0.f, a1 = 0.f, a2 = 0.f, a3 = 0.f, a4 = 0.f, a5 = 0.f, a6 = 0.f, a7 = 0.f;
        for (int j = 0; j < dpad; j += 16) {
            int s[4];
            uint4v v[4];
#pragma unroll
            for (int u = 0; u < 4; ++u) s[u] = cl[j + u * 4 + g];   // 4-addr LDS broadcast
#pragma unroll
            for (int u = 0; u < 4; ++u) v[u] = xs4[((size_t)s[u] << 4) + l16];  // 4 in flight
#pragma unroll
            for (int u = 0; u < 4; ++u) {
                a0 += lo_bf(v[u].x); a1 += hi_bf(v[u].x);
                a2 += lo_bf(v[u].y); a3 += hi_bf(v[u].y);
                a4 += lo_bf(v[u].z); a5 += hi_bf(v[u].z);
                a6 += lo_bf(v[u].w); a7 += hi_bf(v[u].w);
            }
        }
        // combine the 4 edge groups
        a0 += __shfl_xor(a0, 16, 64); a0 += __shfl_xor(a0, 32, 64);
        a1 += __shfl_xor(a1, 16, 64); a1 += __shfl_xor(a1, 32, 64);
        a2 += __shfl_xor(a2, 16, 64); a2 += __shfl_xor(a2, 32, 64);
        a3 += __shfl_xor(a3, 16, 64); a3 += __shfl_xor(a3, 32, 64);
        a4 += __shfl_xor(a4, 16, 64); a4 += __shfl_xor(a4, 32, 64);
        a5 += __shfl_xor(a5, 16, 64); a5 += __shfl_xor(a5, 32, 64);
        a6 += __shfl_xor(a6, 16, 64); a6 += __shfl_xor(a6, 32, 64);
        a7 += __shfl_xor(a7, 16, 64); a7 += __shfl_xor(a7, 32, 64);
        if (g == 0) {
            uint4v vs = xs4[((size_t)node << 4) + l16];  // self-loop
            a0 += lo_bf(vs.x); a1 += hi_bf(vs.x);
            a2 += lo_bf(vs.y); a3 += hi_bf(vs.y);
            a4 += lo_bf(vs.z); a5 += hi_bf(vs.z);
            a6 += lo_bf(vs.w); a7 += hi_bf(vs.w);
            short8 o;
            o.s0 = f2bf(fmaxf(fmaf(a0, dv, bgA.x), 0.f));
            o.s1 = f2bf(fmaxf(fmaf(a1, dv, bgA.y), 0.f));
            o.s2 = f2bf(fmaxf(fmaf(a2, dv, bgA.z), 0.f));
            o.s3 = f2bf(fmaxf(fmaf(a3, dv, bgA.w), 0.f));
            o.s4 = f2bf(fmaxf(fmaf(a4, dv, bgB.x), 0.f));
            o.s5 = f2bf(fmaxf(fmaf(a5, dv, bgB.y), 0.f));
            o.s6 = f2bf(fmaxf(fmaf(a6, dv, bgB.z), 0.f));
            o.s7 = f2bf(fmaxf(fmaf(a7, dv, bgB.w), 0.f));
            *reinterpret_cast<short8*>(h2 + ((size_t)node << 7) + l16 * 8) = o;
        }
    }
}

// ---------- gemmB: 2 node-tiles per wave (128 rows/block), weights loaded once ----
__global__ __launch_bounds__(256) void gemmB_kernel(const short* __restrict__ h2,
                                                    const short* __restrict__ Wt1,
                                                    const short* __restrict__ W2t,
                                                    const float* __restrict__ b1,
                                                    const float* __restrict__ b2,
                                                    float* __restrict__ q) {
    __shared__ short hq_l[4][16][264];  // per-wave private 16x256 tile (reused per node-tile)
    const int wave = threadIdx.x >> 6;
    const int lane = threadIdx.x & 63;
    const int quad = lane >> 4;
    const int l16  = lane & 15;
    const int node0 = blockIdx.x * 128 + wave * 32;

    int r0 = node0 + l16;
    int r1 = node0 + 16 + l16;
    if (r0 >= N_NODES) r0 = N_NODES - 1;
    if (r1 >= N_NODES) r1 = N_NODES - 1;

    f32x4 acc0[16] = {}, acc1[16] = {};
#pragma unroll
    for (int kc = 0; kc < 4; ++kc) {
        short8 xf0 = *reinterpret_cast<const short8*>(h2 + (size_t)r0 * 128 + kc * 32 + quad * 8);
        short8 xf1 = *reinterpret_cast<const short8*>(h2 + (size_t)r1 * 128 + kc * 32 + quad * 8);
#pragma unroll
        for (int t = 0; t < 16; ++t) {
            short8 wfrag = *reinterpret_cast<const short8*>(Wt1 + (size_t)(t * 16 + l16) * 128 + kc * 32 + quad * 8);
            acc0[t] = __builtin_amdgcn_mfma_f32_16x16x32_bf16(wfrag, xf0, acc0[t], 0, 0, 0);
            acc1[t] = __builtin_amdgcn_mfma_f32_16x16x32_bf16(wfrag, xf1, acc1[t], 0, 0, 0);
        }
    }

#pragma unroll
    for (int half = 0; half < 2; ++half) {
        const f32x4* acc = half ? acc1 : acc0;
        const int nb = node0 + half * 16;
#pragma unroll
        for (int t = 0; t < 16; ++t) {
            short4v o;
#pragma unroll
            for (int r = 0; r < 4; ++r)
                ((short*)&o)[r] = f2bf(fmaxf(acc[t][r] + b1[t * 16 + quad * 4 + r], 0.f));
            *reinterpret_cast<short4v*>(&hq_l[wave][l16][t * 16 + quad * 4]) = o;
        }
        // wave-private tile; DS ops are in-order per wave -> no barrier needed

        f32x4 a2 = {};
#pragma unroll
        for (int kc = 0; kc < 8; ++kc) {
            short8 afrag = *reinterpret_cast<const short8*>(&hq_l[wave][l16][kc * 32 + quad * 8]);
            short8 bfrag = *reinterpret_cast<const short8*>(W2t + (size_t)l16 * 256 + kc * 32 + quad * 8);
            a2 = __builtin_amdgcn_mfma_f32_16x16x32_bf16(afrag, bfrag, a2, 0, 0, 0);
        }
        if (l16 < 10) {
            float bv = b2[l16];
#pragma unroll
            for (int r = 0; r < 4; ++r) {
                int nd = nb + quad * 4 + r;
                if (nd < N_NODES) q[(size_t)nd * 10 + l16] = a2[r] + bv;
            }
        }
    }
}

extern "C" void kernel_launch(void* const* d_in, const int* in_sizes, int n_in,
                              void* d_out, int out_size, void* d_ws, size_t ws_size,
                              hipStream_t stream) {
    const float* x     = (const float*)d_in[0];
    const int*   ei    = (const int*)d_in[1];
    const float* W_enc = (const float*)d_in[2];
    const float* b_enc = (const float*)d_in[3];
    const float* W_gcn = (const float*)d_in[4];
    const float* b_gcn = (const float*)d_in[5];
    const float* W1    = (const float*)d_in[6];
    const float* b1    = (const float*)d_in[7];
    const float* W2    = (const float*)d_in[8];
    const float* b2    = (const float*)d_in[9];
    float* q = (float*)d_out;

    const int E = in_sizes[1] / 2;
    const int* srcv = ei;
    const int* dstv = ei + E;

    // workspace layout (bytes)
    char* ws = (char*)d_ws;
    const size_t XSB = (size_t)(NB * 64) * 128 * sizeof(short);  // 25,608,192 (incl. pad rows)
    short* xs  = (short*)(ws);
    short* h2  = (short*)(ws + XSB);
    int*   part= (int*)  (ws + 2 * XSB);                         // 16,005,120
    char*  tail = ws + 2 * XSB + (size_t)NB * BCAP * sizeof(int);
    int*   bcr = (int*)(tail);                                   // 8 KB slot
    short* Wte = (short*)(tail + 8192);
    short* Wtg = (short*)(tail + 8192 + 32768);
    short* Wt1 = (short*)(tail + 8192 + 65536);
    short* W2t = (short*)(tail + 8192 + 131072);
    // end ~= 67.7 MB

    prep_kernel<<<279, 256, 0, stream>>>(W_enc, W_gcn, W1, W2, Wte, Wtg, Wt1, W2t, bcr);
    part_kernel<<<(E + CHUNK - 1) / CHUNK, 512, 0, stream>>>(srcv, dstv, bcr, part, E);
    gemmA_kernel<<<NB, 256, 0, stream>>>(x, Wte, Wtg, b_enc, bcr, part, xs);
    agg_kernel<<<NB, 512, 0, stream>>>(xs, bcr, part, b_gcn, h2);
    gemmB_kernel<<<(N_NODES + 127) / 128, 256, 0, stream>>>(h2, Wt1, W2t, b1, b2, q);
}